// Round 4
// baseline (274.195 us; speedup 1.0000x reference)
//
#include <hip/hip_runtime.h>
#include <math.h>

#define NPG   200                 // nodes per graph
#define HDIM  128
#define NG    256
#define NT_T  (NG * NPG)          // 51200
#define EPG_  3200
#define E_T   (NG * EPG_)         // 819200
#define KP1   224                 // layer-1 K (200) padded to mult of 32
#define APITCH 224                // A' row pitch (zero cols >= 200)
#define XPAD  224                 // converted-X row pitch (zero cols >= 200)
#define TTP   232                 // Tt LDS pitch (shorts): 464B, 16B-aligned rows
#define W1SZ  (256 * KP1)
#define W2SZ  (256 * HDIM)

// prep-kernel grid partition
#define NB_ADJ (2 * NG)                       // 512
#define NB_CX  (2 * NT_T * 28 / 256)          // 11200
#define NB_CW  ((2 * (W1SZ + W2SZ)) / 256)    // 704
#define NB_PREP (NB_ADJ + NB_CX + NB_CW)

typedef short short8 __attribute__((ext_vector_type(8)));
typedef float f32x4  __attribute__((ext_vector_type(4)));

__device__ __forceinline__ unsigned short f2bf(float f) {
    union { float f; unsigned int u; } v; v.f = f;
    unsigned int u = v.u;
    u += 0x7FFFu + ((u >> 16) & 1u);       // RNE
    return (unsigned short)(u >> 16);
}

// ---------------------------------------------------------------------------
// Union prep kernel: [0,512) adjacency build; [512,11712) X convert;
// [11712,12416) W convert.  (unchanged)
// ---------------------------------------------------------------------------
__global__ __launch_bounds__(256) void prep_kernel(
        const int* __restrict__ sc_ei, const int* __restrict__ fc_ei,
        const float* __restrict__ sc_x, const float* __restrict__ fc_x,
        const float* __restrict__ s1r, const float* __restrict__ s1o,
        const float* __restrict__ f1r, const float* __restrict__ f1o,
        const float* __restrict__ s2r, const float* __restrict__ s2o,
        const float* __restrict__ f2r, const float* __restrict__ f2o,
        unsigned short* __restrict__ A, unsigned short* __restrict__ xb,
        unsigned short* __restrict__ wb) {
    const int b = blockIdx.x, t = threadIdx.x;

    if (b < NB_ADJ) {
        // ---- adjacency: A' = count/max(deg,1) bf16, [branch][g][dst][src pad 224]
        __shared__ unsigned int cnt[10000];    // 200*200 u8 counters in u32
        __shared__ float invdeg[200];
        const int branch = b >> 8, g = b & 255;
        const int* ei = branch ? fc_ei : sc_ei;

        for (int i = t; i < 10000; i += 256) cnt[i] = 0u;
        __syncthreads();
        const int ebase = g * EPG_;
        for (int i = t; i < EPG_; i += 256) {
            int src = ei[ebase + i];
            int dst = ei[E_T + ebase + i];
            int idx = (dst - g * NPG) * NPG + (src - g * NPG);
            atomicAdd(&cnt[idx >> 2], 1u << ((idx & 3) * 8));
        }
        __syncthreads();
        if (t < NPG) {
            unsigned int s = 0;
            for (int w = 0; w < 50; ++w) {
                unsigned int v = cnt[t * 50 + w];
                s += (v & 0xFFu) + ((v >> 8) & 0xFFu) + ((v >> 16) & 0xFFu) + ((v >> 24) & 0xFFu);
            }
            invdeg[t] = 1.0f / fmaxf((float)s, 1.0f);
        }
        __syncthreads();
        unsigned short* Ag = A + ((size_t)branch * NG + g) * NPG * APITCH;
        for (int q = t; q < NPG * (APITCH / 4); q += 256) {
            int row = q / 56;
            int c4  = (q - row * 56) * 4;
            float inv = invdeg[row];
            ushort4 o;
            unsigned short* po = (unsigned short*)&o;
#pragma unroll
            for (int j = 0; j < 4; ++j) {
                int col = c4 + j;
                float v = 0.0f;
                if (col < NPG) {
                    unsigned int w = cnt[row * 50 + (col >> 2)];
                    v = (float)((w >> ((col & 3) * 8)) & 0xFFu) * inv;
                }
                po[j] = f2bf(v);
            }
            *(ushort4*)&Ag[row * APITCH + c4] = o;
        }
    } else if (b < NB_ADJ + NB_CX) {
        // ---- X fp32 [NT,200] -> bf16 [NT,224]
        int c = (b - NB_ADJ) * 256 + t;
        int branch = c / (NT_T * 28);
        int rem = c - branch * (NT_T * 28);
        int node = rem / 28;
        int koff = (rem - node * 28) * 8;
        const float* x = branch ? fc_x : sc_x;
        uint4 o;
        if (koff < 200) {
            const float* p = x + (size_t)node * 200 + koff;
            float4 a = *(const float4*)p;
            float4 bb = *(const float4*)(p + 4);
            o.x = (unsigned)f2bf(a.x) | ((unsigned)f2bf(a.y) << 16);
            o.y = (unsigned)f2bf(a.z) | ((unsigned)f2bf(a.w) << 16);
            o.z = (unsigned)f2bf(bb.x) | ((unsigned)f2bf(bb.y) << 16);
            o.w = (unsigned)f2bf(bb.z) | ((unsigned)f2bf(bb.w) << 16);
        } else {
            o.x = o.y = o.z = o.w = 0u;
        }
        *(uint4*)&xb[((size_t)branch * NT_T + node) * XPAD + koff] = o;
    } else {
        // ---- weights -> packed W^T bf16 [br0L1|br1L1|br0L2|br1L2], rel|root rows
        int idx = (b - NB_ADJ - NB_CX) * 256 + t;
        float v = 0.0f;
        if (idx < 2 * W1SZ) {
            int branch = idx / W1SZ, rem = idx - branch * W1SZ;
            int c = rem / KP1, k = rem - c * KP1;
            const float* wr = branch ? f1r : s1r;
            const float* wo = branch ? f1o : s1o;
            if (k < 200) v = (c < 128) ? wr[(size_t)k * 128 + c] : wo[(size_t)k * 128 + (c - 128)];
        } else {
            int i2 = idx - 2 * W1SZ;
            int branch = i2 / W2SZ, rem = i2 - branch * W2SZ;
            int c = rem / HDIM, k = rem - c * HDIM;
            const float* wr = branch ? f2r : s2r;
            const float* wo = branch ? f2o : s2o;
            v = (c < 128) ? wr[(size_t)k * 128 + c] : wo[(size_t)k * 128 + (c - 128)];
        }
        wb[idx] = f2bf(v);
    }
}

// ---------------------------------------------------------------------------
// Round-11: depth-2 pipelined staging with counted vmcnt (T3/T4).
//
// Round-3 post-mortem: per-step time ~3.5K cycles vs ~500 of work. Cause:
// STAGE(next) was issued BEFORE the ds_reads of the current buffer, and the
// compiler cannot disambiguate dbuf[nxt] writes from dbuf[cur] reads -> it
// inserts s_waitcnt vmcnt(0) BEFORE the reads -> every stage is fully
// serialized (HBM ~900 cyc exposed per step).  MfmaUtil stayed at 16%.
//
// New step structure (per K-tile t, 3-buffer rotation, full unroll):
//   [s_waitcnt vmcnt(4) lgkmcnt(0); s_barrier]   <- waits ONLY for tile t
//                                                   (issued 2 steps ago);
//                                                   tile t+1 stays in flight
//   ds_read fragments from dbuf[t%3]             <- reads BEFORE any stage
//   issue STAGE(t+2) -> dbuf[(t+2)%3]            <- flies for ~2 phases
//   MFMAs
// Race audit: buf[j] rewritten by STAGE(j+3), issued after barrier(j+1);
// all waves' step-j reads are consumed before they reach barrier(j+1). Safe.
// Staging is exec-uniform (256-row tiles, 4 gload_lds per wave) so the
// per-wave vmcnt count is exact; rows 200+ are never read from LDS.
// lgkmcnt(0) in the fence also orders the Tt handoff at the X->agg switch.
//
// Math/MFMA order identical to round-0/3 -> bitwise-identical output.
// LDS: Tt 29,696 + dbuf 3*16,384 + zsum 256 = 79,104 B -> 2 blocks/CU.
// ---------------------------------------------------------------------------
#define FENCE_N4 asm volatile("s_waitcnt vmcnt(4) lgkmcnt(0)\n\ts_barrier" ::: "memory")
#define FENCE_N0 asm volatile("s_waitcnt vmcnt(0) lgkmcnt(0)\n\ts_barrier" ::: "memory")

template<bool IS_L1>
__global__ __launch_bounds__(256, 2) void layer_kernel(
        const unsigned short* __restrict__ Xb,     // L1 input, pitch 224
        const unsigned short* __restrict__ hin,    // L2 input, pitch 128
        const unsigned short* __restrict__ Wall,
        const unsigned short* __restrict__ Aall,
        const float* __restrict__ brel_sc, const float* __restrict__ brel_fc,
        unsigned short* __restrict__ Hout,
        float* __restrict__ z, int zlayer) {
    __shared__ alignas(16) short Tt[64 * TTP];        // 29,696 B
    __shared__ alignas(16) short dbuf[3][8192];       // 3 x 16,384 B
    __shared__ float zsum[64];

    const int tid = threadIdx.x;
    const int lane = tid & 63, wid = tid >> 6;     // 4 waves
    const int l15 = lane & 15, quad = lane >> 4;

    // XCD-pair swizzle decode (1024 blocks)
    const int lin  = blockIdx.x;
    const int half = (lin >> 3) & 1;               // 0/1: channel half
    const int p    = (lin >> 4) * 8 + (lin & 7);   // pair id 0..511
    const int g = p & 255, branch = p >> 8;

    if (tid < 64) zsum[tid] = 0.0f;

    const int KITER = IS_L1 ? 7 : 4;
    const int XP    = IS_L1 ? XPAD : HDIM;
    const int WP    = IS_L1 ? KP1 : HDIM;
    const unsigned short* X = (IS_L1 ? Xb : hin) + (size_t)branch * NT_T * XP;
    const unsigned short* W = Wall + (IS_L1 ? (size_t)branch * W1SZ
                                            : (size_t)2 * W1SZ + (size_t)branch * W2SZ);
    const unsigned short* Xg = X + (size_t)g * NPG * XP;
    const unsigned short* Ag = Aall + ((size_t)branch * NG + g) * NPG * APITCH;

    const int ms = wid & 1;        // node-tile set
    const int ns = wid >> 1;       // channel-tile set

    int nrow[7], xoff[7];
#pragma unroll
    for (int mt = 0; mt < 7; ++mt) {
        int s = (ms * 7 + mt) * 16 + l15;
        nrow[mt] = (s > NPG - 1) ? (NPG - 1) : s;       // clamp; killed by A'=0
        xoff[mt] = nrow[mt] * 64 + quad * 16;           // byte offset in LDS tile
    }
    int wrow[2];
#pragma unroll
    for (int nt = 0; nt < 2; ++nt)
        wrow[nt] = half * 64 + (ns * 2 + nt) * 16 + l15;

    // stage one 256-row x 64B K-tile into dbuf[bsel]; exec-uniform: exactly
    // 4 gload_lds per wave.  Rows 200-255 read neighbor data (in-workspace)
    // and are never read back from LDS.
    auto STAGE = [&](const unsigned short* srcbase, int pitch_sh, int kb_sh, int bsel) {
#pragma unroll
        for (int it = 0; it < 4; ++it) {
            int i = it * 256 + tid;                     // chunk 0..1023
            int row = i >> 2, slot = i & 3;
            const char* gp = (const char*)srcbase
                           + (size_t)row * (pitch_sh * 2) + (size_t)kb_sh * 2 + slot * 16;
            __attribute__((address_space(3))) char* lp =
                ((__attribute__((address_space(3))) char*)&dbuf[bsel][0]) + (size_t)i * 16;
            __builtin_amdgcn_global_load_lds(
                (const __attribute__((address_space(1))) unsigned int*)gp,
                (__attribute__((address_space(3))) unsigned int*)lp, 16, 0, 0);
        }
    };

    f32x4 accT[7][2];   // D[m=s][n=c]
    f32x4 accH[2][7];   // D[m=c][n=d]
#pragma unroll
    for (int mt = 0; mt < 7; ++mt)
#pragma unroll
        for (int nt = 0; nt < 2; ++nt)
#pragma unroll
            for (int r = 0; r < 4; ++r) { accT[mt][nt][r] = 0.0f; accH[nt][mt][r] = 0.0f; }

    // prologue: stage tiles 0 and 1 (both X)
    STAGE(Xg, XP, 0, 0);
    STAGE(Xg, XP, 32, 1);

    // ======== Merged X-scan: transform + root term, tiles from LDS ========
#pragma unroll
    for (int ki = 0; ki < KITER; ++ki) {
        FENCE_N4;                                       // tile ki landed; ki+1 in flight

        const char* bp = (const char*)&dbuf[ki % 3][0];
        short8 xf[7];
#pragma unroll
        for (int mt = 0; mt < 7; ++mt)
            xf[mt] = *(const short8*)(bp + xoff[mt]);
        const int kb = ki * 32 + quad * 8;
        short8 wr[2], wo[2];
#pragma unroll
        for (int nt = 0; nt < 2; ++nt) {
            wr[nt] = *(const short8*)&W[(size_t)wrow[nt] * WP + kb];
            wo[nt] = *(const short8*)&W[(size_t)(128 + wrow[nt]) * WP + kb];
        }

        // stage tile ki+2 (X while available, then A')
        {
            const int ts = ki + 2;
            if (ts < KITER)           STAGE(Xg, XP, ts * 32, ts % 3);
            else if (ts - KITER < 7)  STAGE(Ag, APITCH, (ts - KITER) * 32, ts % 3);
        }

#pragma unroll
        for (int mt = 0; mt < 7; ++mt)
#pragma unroll
            for (int nt = 0; nt < 2; ++nt)
                accT[mt][nt] = __builtin_amdgcn_mfma_f32_16x16x32_bf16(
                    xf[mt], wr[nt], accT[mt][nt], 0, 0, 0);
#pragma unroll
        for (int nt = 0; nt < 2; ++nt)
#pragma unroll
            for (int mt = 0; mt < 7; ++mt)
                accH[nt][mt] = __builtin_amdgcn_mfma_f32_16x16x32_bf16(
                    wo[nt], xf[mt], accH[nt][mt], 0, 0, 0);
    }

    // accT -> Tt (lane holds s = quad*4+r, c = l15); visibility ensured by the
    // lgkmcnt(0)+barrier in the next fence.
#pragma unroll
    for (int mt = 0; mt < 7; ++mt) {
        int s0 = (ms * 7 + mt) * 16 + quad * 4;
#pragma unroll
        for (int nt = 0; nt < 2; ++nt) {
            int c = (ns * 2 + nt) * 16 + l15;
            ushort4 o;
            unsigned short* po = (unsigned short*)&o;
#pragma unroll
            for (int r = 0; r < 4; ++r) po[r] = f2bf(accT[mt][nt][r]);
            *(ushort4*)&Tt[c * TTP + s0] = o;
        }
    }

    // ======== Agg K-loop over s: accH += Trel(LDS) x A'(staged LDS) ========
#pragma unroll
    for (int ki = 0; ki < 7; ++ki) {
        if (ki < 6) FENCE_N4; else FENCE_N0;            // A'[ki] landed

        const char* bp = (const char*)&dbuf[(KITER + ki) % 3][0];
        const int k0 = ki * 32 + quad * 8;
        short8 tf[2];
#pragma unroll
        for (int ct = 0; ct < 2; ++ct)
            tf[ct] = *(const short8*)&Tt[((ns * 2 + ct) * 16 + l15) * TTP + k0];
        short8 afr[7];
#pragma unroll
        for (int dt = 0; dt < 7; ++dt)
            afr[dt] = *(const short8*)(bp + xoff[dt]);

        if (ki + 2 < 7) STAGE(Ag, APITCH, (ki + 2) * 32, (KITER + ki + 2) % 3);

#pragma unroll
        for (int ct = 0; ct < 2; ++ct)
#pragma unroll
            for (int dt = 0; dt < 7; ++dt)
                accH[ct][dt] = __builtin_amdgcn_mfma_f32_16x16x32_bf16(
                    tf[ct], afr[dt], accH[ct][dt], 0, 0, 0);
    }

    // Epilogue: lane holds (c = quad*4+r, d = l15); relu + brel, pool, H store
    const float* brel = branch ? brel_fc : brel_sc;
    unsigned short* Hb = Hout + (size_t)branch * NT_T * HDIM;

#pragma unroll
    for (int ct = 0; ct < 2; ++ct) {
        const int c0 = (ns * 2 + ct) * 16 + quad * 4;      // local ch 0..63
        float bb[4], part[4];
#pragma unroll
        for (int r = 0; r < 4; ++r) { bb[r] = brel[half * 64 + c0 + r]; part[r] = 0.0f; }
#pragma unroll
        for (int dt = 0; dt < 7; ++dt) {
            const int d = (ms * 7 + dt) * 16 + l15;
            if (d < NPG) {
                size_t node = (size_t)g * NPG + d;
                ushort4 o;
                unsigned short* po = (unsigned short*)&o;
#pragma unroll
                for (int r = 0; r < 4; ++r) {
                    float v = fmaxf(accH[ct][dt][r] + bb[r], 0.0f);
                    part[r] += v;
                    po[r] = f2bf(v);
                }
                if (IS_L1) *(ushort4*)&Hb[node * HDIM + half * 64 + c0] = o;  // L2: pool only
            }
        }
        // butterfly over the 16 l15 lanes (d-dim), then 1 LDS atomic per channel
#pragma unroll
        for (int r = 0; r < 4; ++r) {
            float v = part[r];
            v += __shfl_xor(v, 1);
            v += __shfl_xor(v, 2);
            v += __shfl_xor(v, 4);
            v += __shfl_xor(v, 8);
            if (l15 == 0) atomicAdd(&zsum[c0 + r], v);
        }
    }
    __syncthreads();

    if (tid < 64)
        z[(size_t)g * 512 + branch * 256 + zlayer + half * 64 + tid] =
            zsum[tid] * (branch ? 1.0f : (1.0f / 200.0f));
}

// ---------------------------------------------------------------------------
// MLP head (fp32): z[512] -> relu(lin1)[128] -> relu(lin2)[64] -> lin3[2]
// -> log_softmax. One block per graph.  (unchanged)
// ---------------------------------------------------------------------------
__global__ __launch_bounds__(128) void mlp_kernel(const float* __restrict__ z,
                                                  const float* __restrict__ w1, const float* __restrict__ b1,
                                                  const float* __restrict__ w2, const float* __restrict__ b2,
                                                  const float* __restrict__ w3, const float* __restrict__ b3,
                                                  float* __restrict__ out) {
    __shared__ float zs[512];
    __shared__ float l1[128];
    __shared__ float l2[64];
    __shared__ float logits[2];
    int g = blockIdx.x, t = threadIdx.x;

#pragma unroll
    for (int i = 0; i < 4; ++i) zs[t + 128 * i] = z[(size_t)g * 512 + t + 128 * i];
    __syncthreads();

    float s = b1[t];
#pragma unroll 8
    for (int k = 0; k < 512; ++k) s = fmaf(zs[k], w1[k * 128 + t], s);
    l1[t] = fmaxf(s, 0.0f);
    __syncthreads();

    if (t < 64) {
        float s2 = b2[t];
#pragma unroll 8
        for (int k = 0; k < 128; ++k) s2 = fmaf(l1[k], w2[k * 64 + t], s2);
        l2[t] = fmaxf(s2, 0.0f);
    }
    __syncthreads();

    if (t < 2) {
        float s3 = b3[t];
        for (int k = 0; k < 64; ++k) s3 = fmaf(l2[k], w3[k * 2 + t], s3);
        logits[t] = s3;
    }
    __syncthreads();

    if (t < 2) {
        float m = fmaxf(logits[0], logits[1]);
        float lse = m + logf(expf(logits[0] - m) + expf(logits[1] - m));
        out[(size_t)g * 2 + t] = logits[t] - lse;
    }
}

// ---------------------------------------------------------------------------
extern "C" void kernel_launch(void* const* d_in, const int* in_sizes, int n_in,
                              void* d_out, int out_size, void* d_ws, size_t ws_size,
                              hipStream_t stream) {
    const float* sc_x = (const float*)d_in[0];
    const float* fc_x = (const float*)d_in[1];
    const int* sc_ei  = (const int*)d_in[2];
    const int* fc_ei  = (const int*)d_in[3];
    const float* sc1_wrel = (const float*)d_in[5];
    const float* sc1_brel = (const float*)d_in[6];
    const float* sc1_wroot = (const float*)d_in[7];
    const float* sc2_wrel = (const float*)d_in[8];
    const float* sc2_brel = (const float*)d_in[9];
    const float* sc2_wroot = (const float*)d_in[10];
    const float* fc1_wrel = (const float*)d_in[11];
    const float* fc1_brel = (const float*)d_in[12];
    const float* fc1_wroot = (const float*)d_in[13];
    const float* fc2_wrel = (const float*)d_in[14];
    const float* fc2_brel = (const float*)d_in[15];
    const float* fc2_wroot = (const float*)d_in[16];
    const float* lin1_w = (const float*)d_in[17];
    const float* lin1_b = (const float*)d_in[18];
    const float* lin2_w = (const float*)d_in[19];
    const float* lin2_b = (const float*)d_in[20];
    const float* lin3_w = (const float*)d_in[21];
    const float* lin3_b = (const float*)d_in[22];

    // Workspace (shorts unless noted): Xb | A' | h | W | z  (~119 MB)
    unsigned short* Xb = (unsigned short*)d_ws;                 // 2*51200*224
    unsigned short* Ab = Xb + (size_t)2 * NT_T * XPAD;          // 2*256*200*224
    unsigned short* h  = Ab + (size_t)2 * NG * NPG * APITCH;    // 2*51200*128
    unsigned short* Wb = h + (size_t)2 * NT_T * HDIM;           // 2*(W1SZ+W2SZ)
    float* z = (float*)(Wb + (size_t)2 * (W1SZ + W2SZ));        // 256*512 fp32

    prep_kernel<<<NB_PREP, 256, 0, stream>>>(
        sc_ei, fc_ei, sc_x, fc_x,
        sc1_wrel, sc1_wroot, fc1_wrel, fc1_wroot,
        sc2_wrel, sc2_wroot, fc2_wrel, fc2_wroot,
        Ab, Xb, Wb);

    layer_kernel<true><<<1024, 256, 0, stream>>>(
        Xb, h, Wb, Ab, sc1_brel, fc1_brel, h, z, 0);
    layer_kernel<false><<<1024, 256, 0, stream>>>(
        Xb, h, Wb, Ab, sc2_brel, fc2_brel, h, z, 128);

    mlp_kernel<<<NG, 128, 0, stream>>>(z, lin1_w, lin1_b, lin2_w, lin2_b,
                                       lin3_w, lin3_b, (float*)d_out);
}

// Round 7
// 268.835 us; speedup vs baseline: 1.0199x; 1.0199x over previous
//
#include <hip/hip_runtime.h>
#include <math.h>

#define NPG   200                 // nodes per graph
#define HDIM  128
#define NG    256
#define NT_T  (NG * NPG)          // 51200
#define EPG_  3200
#define E_T   (NG * EPG_)         // 819200
#define KP1   224                 // layer-1 K (200) padded to mult of 32 (W pitch)
#define TTP   232                 // Tt LDS pitch (shorts)
#define W1SZ  (256 * KP1)
#define W2SZ  (256 * HDIM)

#define XSTR1 40960               // X/A' slab stride, shorts (81,920 B; data 80,000)
#define HSTR  25600               // h slab stride, shorts (51,200 B exact)
#define ALDS  80000               // A' region byte offset in LDS arena
#define ARENA_SZ 160128           // 160,000 data + 128 zeroed pad

// prep-kernel grid partition
#define NB_ADJ (2 * NG)                       // 512
#define NB_CX  (2 * NG * 5120 / 256)          // 10240 (slab-based, incl. pad)
#define NB_CW  ((2 * (W1SZ + W2SZ)) / 256)    // 704
#define NB_PREP (NB_ADJ + NB_CX + NB_CW)

typedef short short8 __attribute__((ext_vector_type(8)));
typedef float f32x4  __attribute__((ext_vector_type(4)));

__device__ __forceinline__ unsigned short f2bf(float f) {
    union { float f; unsigned int u; } v; v.f = f;
    unsigned int u = v.u;
    u += 0x7FFFu + ((u >> 16) & 1u);       // RNE
    return (unsigned short)(u >> 16);
}

// ---------------------------------------------------------------------------
// Union prep kernel: [0,512) adjacency; [512,10752) X convert (slab-based,
// zero-fills slab pad); [10752,11456) W convert.
// Layouts: X/A' pitch 200 shorts (400 B rows), slab stride 40,960 shorts;
// h pitch 128 shorts, slab stride 25,600.  All slab pads zeroed (NaN safety).
// ---------------------------------------------------------------------------
__global__ __launch_bounds__(256) void prep_kernel(
        const int* __restrict__ sc_ei, const int* __restrict__ fc_ei,
        const float* __restrict__ sc_x, const float* __restrict__ fc_x,
        const float* __restrict__ s1r, const float* __restrict__ s1o,
        const float* __restrict__ f1r, const float* __restrict__ f1o,
        const float* __restrict__ s2r, const float* __restrict__ s2o,
        const float* __restrict__ f2r, const float* __restrict__ f2o,
        unsigned short* __restrict__ A, unsigned short* __restrict__ xb,
        unsigned short* __restrict__ wb) {
    const int b = blockIdx.x, t = threadIdx.x;

    if (b < NB_ADJ) {
        // ---- adjacency: A' = count/max(deg,1) bf16, [branch*256+g][dst][src], pitch 200
        __shared__ unsigned int cnt[10000];    // 200*200 u8 counters in u32
        __shared__ float invdeg[200];
        const int branch = b >> 8, g = b & 255;
        const int* ei = branch ? fc_ei : sc_ei;

        for (int i = t; i < 10000; i += 256) cnt[i] = 0u;
        __syncthreads();
        const int ebase = g * EPG_;
        for (int i = t; i < EPG_; i += 256) {
            int src = ei[ebase + i];
            int dst = ei[E_T + ebase + i];
            int idx = (dst - g * NPG) * NPG + (src - g * NPG);
            atomicAdd(&cnt[idx >> 2], 1u << ((idx & 3) * 8));
        }
        __syncthreads();
        if (t < NPG) {
            unsigned int s = 0;
            for (int w = 0; w < 50; ++w) {
                unsigned int v = cnt[t * 50 + w];
                s += (v & 0xFFu) + ((v >> 8) & 0xFFu) + ((v >> 16) & 0xFFu) + ((v >> 24) & 0xFFu);
            }
            invdeg[t] = 1.0f / fmaxf((float)s, 1.0f);
        }
        __syncthreads();
        unsigned short* Ag = A + ((size_t)branch * NG + g) * XSTR1;
        for (int q = t; q < 10000; q += 256) {
            int row = q / 50;
            int c4  = (q - row * 50) * 4;
            float inv = invdeg[row];
            unsigned int w = cnt[q];             // word holds cols c4..c4+3
            ushort4 o;
            unsigned short* po = (unsigned short*)&o;
#pragma unroll
            for (int j = 0; j < 4; ++j)
                po[j] = f2bf((float)((w >> (j * 8)) & 0xFFu) * inv);
            *(ushort4*)&Ag[row * 200 + c4] = o;
        }
        // zero slab pad [40000, 40960) shorts
        if (t < 240) {
            ushort4 zo = {0, 0, 0, 0};
            *(ushort4*)&Ag[40000 + t * 4] = zo;
        }
    } else if (b < NB_ADJ + NB_CX) {
        // ---- X fp32 [node,200] -> bf16 slabs pitch 200, stride 40960, pad zeroed
        int c = (b - NB_ADJ) * 256 + t;          // 0 .. 2*256*5120-1
        int slab = c / 5120;                     // branch*256 + g
        int ci = c - slab * 5120;                // chunk (8 shorts) within slab
        uint4 o;
        if (ci < 5000) {
            int n  = ci / 25;                    // node within graph
            int k8 = ci - n * 25;
            int branch = slab >> 8, g = slab & 255;
            const float* x = branch ? fc_x : sc_x;
            const float* p = x + ((size_t)g * NPG + n) * 200 + k8 * 8;
            float4 a  = *(const float4*)p;
            float4 bb = *(const float4*)(p + 4);
            o.x = (unsigned)f2bf(a.x) | ((unsigned)f2bf(a.y) << 16);
            o.y = (unsigned)f2bf(a.z) | ((unsigned)f2bf(a.w) << 16);
            o.z = (unsigned)f2bf(bb.x) | ((unsigned)f2bf(bb.y) << 16);
            o.w = (unsigned)f2bf(bb.z) | ((unsigned)f2bf(bb.w) << 16);
        } else {
            o.x = o.y = o.z = o.w = 0u;          // slab pad
        }
        *(uint4*)&xb[(size_t)slab * XSTR1 + (size_t)ci * 8] = o;
    } else {
        // ---- weights -> packed W^T bf16 [br0L1|br1L1|br0L2|br1L2], rel|root rows
        int idx = (b - NB_ADJ - NB_CX) * 256 + t;
        float v = 0.0f;
        if (idx < 2 * W1SZ) {
            int branch = idx / W1SZ, rem = idx - branch * W1SZ;
            int c = rem / KP1, k = rem - c * KP1;
            const float* wr = branch ? f1r : s1r;
            const float* wo = branch ? f1o : s1o;
            if (k < 200) v = (c < 128) ? wr[(size_t)k * 128 + c] : wo[(size_t)k * 128 + (c - 128)];
        } else {
            int i2 = idx - 2 * W1SZ;
            int branch = i2 / W2SZ, rem = i2 - branch * W2SZ;
            int c = rem / HDIM, k = rem - c * HDIM;
            const float* wr = branch ? f2r : s2r;
            const float* wo = branch ? f2o : s2o;
            v = (c < 128) ? wr[(size_t)k * 128 + c] : wo[(size_t)k * 128 + (c - 128)];
        }
        wb[idx] = f2bf(v);
    }
}

// ---------------------------------------------------------------------------
// Round-14: identical structure to round-13 (whole-slab LDS residency,
// single-touch row-contiguous staging, linear dest+src, 3 fences), plus a
// NaN-hardening fix: phase-2 X chunk index clamped to the row's last real
// chunk (c<=24 for L1).  Without the clamp, X row 199's chunks 25..27 read
// arena[80000..80048) = the A' region head, which is mid-flight /
// uninitialized at phase 2 -> possible NaN bf16 patterns -> 0*NaN = NaN in
// the accumulator.  Clamped lanes re-read chunk 24 (finite real data) which
// multiplies the zeroed W rows k in [200,224) -> exact 0 contribution.
//
// Safety audit (all other overreads):
//  - phase-4 A' rows <199, chunks 25..27: read NEXT A' row's staged data
//    (finite; A' fully landed at F2); annihilated by zeroed Tt cols >=200.
//  - phase-4 A' row 199: reads arena tail [160000,160048) - explicitly
//    zeroed before staging.
//  - Tt: cols >=200 written 0; full [0,224) x [0,128) coverage before F3.
// Fences: F1 vmcnt(10)+bar (X landed; 10 A' in flight), F2 vmcnt(0)
// lgkm(0)+bar, F3 lgkm(0)+bar.  vmcnt FIFO: L1 10X+10A', L2 7X+10A';
// vmcnt(10) retires exactly the X loads in both.
// MFMA order/operands bitwise identical to the 281us round-0 kernel.
// ---------------------------------------------------------------------------
template<bool IS_L1>
__global__ __launch_bounds__(512, 1) void layer_kernel(
        const unsigned short* __restrict__ Xb,     // L1 input slabs, pitch 200
        const unsigned short* __restrict__ hin,    // L2 input slabs, pitch 128
        const unsigned short* __restrict__ Wall,
        const unsigned short* __restrict__ Aall,
        const float* __restrict__ brel_sc, const float* __restrict__ brel_fc,
        unsigned short* __restrict__ Hout,
        float* __restrict__ z, int zlayer) {
    __shared__ __attribute__((aligned(16))) char arena[ARENA_SZ];

    constexpr int KITER = IS_L1 ? 7 : 4;
    constexpr int WP    = IS_L1 ? KP1 : HDIM;
    constexpr int XCH   = IS_L1 ? 25 : 16;       // 16B chunks per row
    constexpr int XROWB = IS_L1 ? 400 : 256;     // LDS/global row pitch bytes
    constexpr int XSLABCH = 200 * XCH;           // 5000 / 3200
    constexpr int XFULL   = XSLABCH / 512;       // 9 / 6 full insts (+1 overlap)
    constexpr int XSTRIDE = IS_L1 ? XSTR1 : HSTR;

    const int tid = threadIdx.x;
    const int lane = tid & 63, wid = tid >> 6;   // 8 waves
    const int l15 = lane & 15, quad = lane >> 4;
    const int ms = wid & 1, ns = wid >> 1;       // node half x channel quarter

    const int g = blockIdx.x & 255, branch = blockIdx.x >> 8;

    const unsigned short* Xg = (IS_L1 ? Xb : hin) + ((size_t)branch * NG + g) * XSTRIDE;
    const unsigned short* W  = Wall + (IS_L1 ? (size_t)branch * W1SZ
                                             : (size_t)2 * W1SZ + (size_t)branch * W2SZ);
    const unsigned short* Ag = Aall + ((size_t)branch * NG + g) * XSTR1;

    // zero arena tail pad (A' row-199 chunk overreads land here)
    if (tid < 32) *(unsigned int*)(arena + 160000 + tid * 4) = 0u;

    // ---- stage X slab, then A' slab (linear dest, linear source)
    {
        __attribute__((address_space(3))) char* lx =
            (__attribute__((address_space(3))) char*)&arena[0];
        for (int j = 0; j <= XFULL; ++j) {
            int i = (j < XFULL) ? (j * 512 + tid) : (XSLABCH - 512 + tid);
            const char* gp = (const char*)Xg + (size_t)i * 16;
            __builtin_amdgcn_global_load_lds(
                (const __attribute__((address_space(1))) unsigned int*)gp,
                (__attribute__((address_space(3))) unsigned int*)(lx + (size_t)i * 16),
                16, 0, 0);
        }
        __builtin_amdgcn_sched_barrier(0);
        __attribute__((address_space(3))) char* la =
            (__attribute__((address_space(3))) char*)&arena[ALDS];
        for (int j = 0; j <= 9; ++j) {
            int i = (j < 9) ? (j * 512 + tid) : (5000 - 512 + tid);
            const char* gp = (const char*)Ag + (size_t)i * 16;
            __builtin_amdgcn_global_load_lds(
                (const __attribute__((address_space(1))) unsigned int*)gp,
                (__attribute__((address_space(3))) unsigned int*)(la + (size_t)i * 16),
                16, 0, 0);
        }
    }

    int nrow[7];
#pragma unroll
    for (int mt = 0; mt < 7; ++mt) {
        int s = (ms * 7 + mt) * 16 + l15;
        nrow[mt] = (s > NPG - 1) ? (NPG - 1) : s;   // clamp; killed downstream
    }
    int wrow[2];
#pragma unroll
    for (int nt = 0; nt < 2; ++nt)
        wrow[nt] = (ns * 2 + nt) * 16 + l15;        // ch row 0..127

    f32x4 accT[7][2];   // D[m=s][n=c]
    f32x4 accH[2][7];   // D[m=c][n=d]
#pragma unroll
    for (int mt = 0; mt < 7; ++mt)
#pragma unroll
        for (int nt = 0; nt < 2; ++nt)
#pragma unroll
            for (int r = 0; r < 4; ++r) { accT[mt][nt][r] = 0.0f; accH[nt][mt][r] = 0.0f; }

    // F1: my X loads done (10 outstanding = the A' loads), all-waves sync
    asm volatile("s_waitcnt vmcnt(10)\n\ts_barrier" ::: "memory");

    // ======== Phase 2: merged transform + root (X from LDS, W direct) ========
#pragma unroll
    for (int ki = 0; ki < KITER; ++ki) {
        // chunk index, clamped to the last real chunk of the row (NaN hardening:
        // never read past the staged X row; clamped lanes' k>=200 contributions
        // are annihilated by the zeroed W rows).
        int cch = ki * 4 + quad;
        if (cch > XCH - 1) cch = XCH - 1;
        short8 xf[7];
#pragma unroll
        for (int mt = 0; mt < 7; ++mt)
            xf[mt] = *(const short8*)(arena + nrow[mt] * XROWB + cch * 16);
        const int kb = ki * 32 + quad * 8;
        short8 wr[2], wo[2];
#pragma unroll
        for (int nt = 0; nt < 2; ++nt) {
            wr[nt] = *(const short8*)&W[(size_t)wrow[nt] * WP + kb];
            wo[nt] = *(const short8*)&W[(size_t)(128 + wrow[nt]) * WP + kb];
        }
#pragma unroll
        for (int mt = 0; mt < 7; ++mt)
#pragma unroll
            for (int nt = 0; nt < 2; ++nt)
                accT[mt][nt] = __builtin_amdgcn_mfma_f32_16x16x32_bf16(
                    xf[mt], wr[nt], accT[mt][nt], 0, 0, 0);
#pragma unroll
        for (int nt = 0; nt < 2; ++nt)
#pragma unroll
            for (int mt = 0; mt < 7; ++mt)
                accH[nt][mt] = __builtin_amdgcn_mfma_f32_16x16x32_bf16(
                    wo[nt], xf[mt], accH[nt][mt], 0, 0, 0);
    }

    // F2: X region dead everywhere; A' fully landed
    asm volatile("s_waitcnt vmcnt(0) lgkmcnt(0)\n\ts_barrier" ::: "memory");

    // Tt overlays X region: lane holds s=quad*4+r, c=l15; cols >=200 ZEROED
    short* Tt = (short*)arena;
#pragma unroll
    for (int mt = 0; mt < 7; ++mt) {
        int s0 = (ms * 7 + mt) * 16 + quad * 4;
#pragma unroll
        for (int nt = 0; nt < 2; ++nt) {
            int c = (ns * 2 + nt) * 16 + l15;
            ushort4 o;
            unsigned short* po = (unsigned short*)&o;
#pragma unroll
            for (int r = 0; r < 4; ++r)
                po[r] = (s0 + r < NPG) ? f2bf(accT[mt][nt][r]) : (unsigned short)0;
            *(ushort4*)&Tt[c * TTP + s0] = o;
        }
    }
    float* zsumf = (float*)(arena + 59392);
    if (tid < 128) zsumf[tid] = 0.0f;

    // F3: Tt + zsum visible
    asm volatile("s_waitcnt lgkmcnt(0)\n\ts_barrier" ::: "memory");

    // ======== Phase 4: agg accH += Tt x A' (all-LDS, no barriers) ========
#pragma unroll
    for (int ki = 0; ki < 7; ++ki) {
        const int k0 = ki * 32 + quad * 8;
        short8 tf[2];
#pragma unroll
        for (int ct = 0; ct < 2; ++ct)
            tf[ct] = *(const short8*)&Tt[((ns * 2 + ct) * 16 + l15) * TTP + k0];
        short8 afr[7];
#pragma unroll
        for (int dt = 0; dt < 7; ++dt)
            afr[dt] = *(const short8*)(arena + ALDS + nrow[dt] * 400 + (ki * 4 + quad) * 16);
#pragma unroll
        for (int ct = 0; ct < 2; ++ct)
#pragma unroll
            for (int dt = 0; dt < 7; ++dt)
                accH[ct][dt] = __builtin_amdgcn_mfma_f32_16x16x32_bf16(
                    tf[ct], afr[dt], accH[ct][dt], 0, 0, 0);
    }

    // Epilogue: lane holds (c = quad*4+r, d = l15); relu + brel, pool, H store
    const float* brel = branch ? brel_fc : brel_sc;
    unsigned short* Hb = Hout + ((size_t)branch * NG + g) * HSTR;

#pragma unroll
    for (int ct = 0; ct < 2; ++ct) {
        const int c0 = (ns * 2 + ct) * 16 + quad * 4;      // global ch 0..127
        float bb[4], part[4];
#pragma unroll
        for (int r = 0; r < 4; ++r) { bb[r] = brel[c0 + r]; part[r] = 0.0f; }
#pragma unroll
        for (int dt = 0; dt < 7; ++dt) {
            const int d = (ms * 7 + dt) * 16 + l15;
            if (d < NPG) {
                ushort4 o;
                unsigned short* po = (unsigned short*)&o;
#pragma unroll
                for (int r = 0; r < 4; ++r) {
                    float v = fmaxf(accH[ct][dt][r] + bb[r], 0.0f);
                    part[r] += v;
                    po[r] = f2bf(v);
                }
                if (IS_L1) *(ushort4*)&Hb[d * HDIM + c0] = o;  // L2: pool only
            }
        }
#pragma unroll
        for (int r = 0; r < 4; ++r) {
            float v = part[r];
            v += __shfl_xor(v, 1);
            v += __shfl_xor(v, 2);
            v += __shfl_xor(v, 4);
            v += __shfl_xor(v, 8);
            if (l15 == 0) atomicAdd(&zsumf[c0 + r], v);
        }
    }
    __syncthreads();

    if (tid < 128)
        z[(size_t)g * 512 + branch * 256 + zlayer + tid] =
            zsumf[tid] * (branch ? 1.0f : (1.0f / 200.0f));
}

// ---------------------------------------------------------------------------
// MLP head (fp32): z[512] -> relu(lin1)[128] -> relu(lin2)[64] -> lin3[2]
// -> log_softmax. One block per graph.  (unchanged)
// ---------------------------------------------------------------------------
__global__ __launch_bounds__(128) void mlp_kernel(const float* __restrict__ z,
                                                  const float* __restrict__ w1, const float* __restrict__ b1,
                                                  const float* __restrict__ w2, const float* __restrict__ b2,
                                                  const float* __restrict__ w3, const float* __restrict__ b3,
                                                  float* __restrict__ out) {
    __shared__ float zs[512];
    __shared__ float l1[128];
    __shared__ float l2[64];
    __shared__ float logits[2];
    int g = blockIdx.x, t = threadIdx.x;

#pragma unroll
    for (int i = 0; i < 4; ++i) zs[t + 128 * i] = z[(size_t)g * 512 + t + 128 * i];
    __syncthreads();

    float s = b1[t];
#pragma unroll 8
    for (int k = 0; k < 512; ++k) s = fmaf(zs[k], w1[k * 128 + t], s);
    l1[t] = fmaxf(s, 0.0f);
    __syncthreads();

    if (t < 64) {
        float s2 = b2[t];
#pragma unroll 8
        for (int k = 0; k < 128; ++k) s2 = fmaf(l1[k], w2[k * 64 + t], s2);
        l2[t] = fmaxf(s2, 0.0f);
    }
    __syncthreads();

    if (t < 2) {
        float s3 = b3[t];
        for (int k = 0; k < 64; ++k) s3 = fmaf(l2[k], w3[k * 2 + t], s3);
        logits[t] = s3;
    }
    __syncthreads();

    if (t < 2) {
        float m = fmaxf(logits[0], logits[1]);
        float lse = m + logf(expf(logits[0] - m) + expf(logits[1] - m));
        out[(size_t)g * 2 + t] = logits[t] - lse;
    }
}

// ---------------------------------------------------------------------------
extern "C" void kernel_launch(void* const* d_in, const int* in_sizes, int n_in,
                              void* d_out, int out_size, void* d_ws, size_t ws_size,
                              hipStream_t stream) {
    const float* sc_x = (const float*)d_in[0];
    const float* fc_x = (const float*)d_in[1];
    const int* sc_ei  = (const int*)d_in[2];
    const int* fc_ei  = (const int*)d_in[3];
    const float* sc1_wrel = (const float*)d_in[5];
    const float* sc1_brel = (const float*)d_in[6];
    const float* sc1_wroot = (const float*)d_in[7];
    const float* sc2_wrel = (const float*)d_in[8];
    const float* sc2_brel = (const float*)d_in[9];
    const float* sc2_wroot = (const float*)d_in[10];
    const float* fc1_wrel = (const float*)d_in[11];
    const float* fc1_brel = (const float*)d_in[12];
    const float* fc1_wroot = (const float*)d_in[13];
    const float* fc2_wrel = (const float*)d_in[14];
    const float* fc2_brel = (const float*)d_in[15];
    const float* fc2_wroot = (const float*)d_in[16];
    const float* lin1_w = (const float*)d_in[17];
    const float* lin1_b = (const float*)d_in[18];
    const float* lin2_w = (const float*)d_in[19];
    const float* lin2_b = (const float*)d_in[20];
    const float* lin3_w = (const float*)d_in[21];
    const float* lin3_b = (const float*)d_in[22];

    // Workspace (shorts unless noted): Xb | A' | h | W | z  (~111 MB)
    unsigned short* Xb = (unsigned short*)d_ws;                  // 2*256*40960
    unsigned short* Ab = Xb + (size_t)2 * NG * XSTR1;            // 2*256*40960
    unsigned short* h  = Ab + (size_t)2 * NG * XSTR1;            // 2*256*25600
    unsigned short* Wb = h + (size_t)2 * NG * HSTR;              // 2*(W1SZ+W2SZ)
    float* z = (float*)(Wb + (size_t)2 * (W1SZ + W2SZ));         // 256*512 fp32

    prep_kernel<<<NB_PREP, 256, 0, stream>>>(
        sc_ei, fc_ei, sc_x, fc_x,
        sc1_wrel, sc1_wroot, fc1_wrel, fc1_wroot,
        sc2_wrel, sc2_wroot, fc2_wrel, fc2_wroot,
        Ab, Xb, Wb);

    layer_kernel<true><<<512, 512, 0, stream>>>(
        Xb, h, Wb, Ab, sc1_brel, fc1_brel, h, z, 0);
    layer_kernel<false><<<512, 512, 0, stream>>>(
        Xb, h, Wb, Ab, sc2_brel, fc2_brel, h, z, 128);

    mlp_kernel<<<NG, 128, 0, stream>>>(z, lin1_w, lin1_b, lin2_w, lin2_b,
                                       lin3_w, lin3_b, (float*)d_out);
}

// Round 8
// 261.701 us; speedup vs baseline: 1.0477x; 1.0273x over previous
//
#include <hip/hip_runtime.h>
#include <math.h>

#define NPG   200                 // nodes per graph
#define HDIM  128
#define NG    256
#define NT_T  (NG * NPG)          // 51200
#define EPG_  3200
#define E_T   (NG * EPG_)         // 819200
#define KP1   224                 // layer-1 K (200) padded to mult of 32 (W pitch)
#define TTP   232                 // Tt LDS pitch (shorts): 464B = 29 chunks (mod8=5, spread)
#define HP    136                 // h LDS pitch (shorts): 272B = 17 chunks (mod8=1, spread)
#define W1SZ  (256 * KP1)
#define W2SZ  (256 * HDIM)

#define XSTR1 40960               // X slab stride, shorts (81,920 B; data 80,000)
#define CBLOB 40960               // cnt blob bytes/slab: 40,000 cnt + 800 invdeg + 160 pad

// LDS arena offsets (bytes)
#define WINOFF 80000              // A' window dbuf: 2 x 16,000 (pitch 40 shorts = 5 chunks)
#define WINSZ  16000
#define CNTOFF 112000             // cnt blob: 40,960
#define IDGOFF (CNTOFF + 40000)   // invdeg f32[200] inside blob
#define ZSOFF  152960             // zsum1[128] | zsum2[128] f32
#define ARENA_SZ2 153984

// prep-kernel grid partition
#define NB_ADJ (2 * NG)                       // 512
#define NB_CX  (2 * NG * 5120 / 256)          // 10240
#define NB_CW  ((2 * (W1SZ + W2SZ)) / 256)    // 704
#define NB_PREP (NB_ADJ + NB_CX + NB_CW)

typedef short short8 __attribute__((ext_vector_type(8)));
typedef float f32x4  __attribute__((ext_vector_type(4)));

__device__ __forceinline__ unsigned short f2bf(float f) {
    union { float f; unsigned int u; } v; v.f = f;
    unsigned int u = v.u;
    u += 0x7FFFu + ((u >> 16) & 1u);       // RNE
    return (unsigned short)(u >> 16);
}

// ---------------------------------------------------------------------------
// Prep: [0,512) adjacency -> RAW u8 counts + fp32 invdeg blob (40,960 B/slab;
// no bf16 A' expansion any more — the fused kernel expands in-LDS);
// [512,10752) X fp32 -> bf16 slabs (pitch 200, stride 40,960 shorts, pad 0);
// [10752,11456) W convert (unchanged packing).
// ---------------------------------------------------------------------------
__global__ __launch_bounds__(256) void prep_kernel(
        const int* __restrict__ sc_ei, const int* __restrict__ fc_ei,
        const float* __restrict__ sc_x, const float* __restrict__ fc_x,
        const float* __restrict__ s1r, const float* __restrict__ s1o,
        const float* __restrict__ f1r, const float* __restrict__ f1o,
        const float* __restrict__ s2r, const float* __restrict__ s2o,
        const float* __restrict__ f2r, const float* __restrict__ f2o,
        unsigned int* __restrict__ C, unsigned short* __restrict__ xb,
        unsigned short* __restrict__ wb) {
    const int b = blockIdx.x, t = threadIdx.x;

    if (b < NB_ADJ) {
        __shared__ unsigned int cnt[10000];    // 200*200 u8 counters in u32
        __shared__ float invdeg[200];
        const int branch = b >> 8, g = b & 255;
        const int* ei = branch ? fc_ei : sc_ei;

        for (int i = t; i < 10000; i += 256) cnt[i] = 0u;
        __syncthreads();
        const int ebase = g * EPG_;
        for (int i = t; i < EPG_; i += 256) {
            int src = ei[ebase + i];
            int dst = ei[E_T + ebase + i];
            int idx = (dst - g * NPG) * NPG + (src - g * NPG);
            atomicAdd(&cnt[idx >> 2], 1u << ((idx & 3) * 8));
        }
        __syncthreads();
        if (t < NPG) {
            unsigned int s = 0;
            for (int w = 0; w < 50; ++w) {
                unsigned int v = cnt[t * 50 + w];
                s += (v & 0xFFu) + ((v >> 8) & 0xFFu) + ((v >> 16) & 0xFFu) + ((v >> 24) & 0xFFu);
            }
            invdeg[t] = 1.0f / fmaxf((float)s, 1.0f);
        }
        __syncthreads();
        // raw blob out: [10000 cnt u32][200 invdeg f32][40 zero u32]
        unsigned int* Cg = C + (size_t)(branch * NG + g) * (CBLOB / 4);
        for (int q = t; q < 10000; q += 256) Cg[q] = cnt[q];
        if (t < 200) ((float*)(Cg + 10000))[t] = invdeg[t];
        if (t < 40) Cg[10200 + t] = 0u;
    } else if (b < NB_ADJ + NB_CX) {
        // ---- X fp32 [node,200] -> bf16 slabs pitch 200, stride 40960, pad zeroed
        int c = (b - NB_ADJ) * 256 + t;          // 0 .. 2*256*5120-1
        int slab = c / 5120;                     // branch*256 + g
        int ci = c - slab * 5120;                // chunk (8 shorts) within slab
        uint4 o;
        if (ci < 5000) {
            int n  = ci / 25;                    // node within graph
            int k8 = ci - n * 25;
            int branch = slab >> 8, g = slab & 255;
            const float* x = branch ? fc_x : sc_x;
            const float* p = x + ((size_t)g * NPG + n) * 200 + k8 * 8;
            float4 a  = *(const float4*)p;
            float4 bb = *(const float4*)(p + 4);
            o.x = (unsigned)f2bf(a.x) | ((unsigned)f2bf(a.y) << 16);
            o.y = (unsigned)f2bf(a.z) | ((unsigned)f2bf(a.w) << 16);
            o.z = (unsigned)f2bf(bb.x) | ((unsigned)f2bf(bb.y) << 16);
            o.w = (unsigned)f2bf(bb.z) | ((unsigned)f2bf(bb.w) << 16);
        } else {
            o.x = o.y = o.z = o.w = 0u;          // slab pad
        }
        *(uint4*)&xb[(size_t)slab * XSTR1 + (size_t)ci * 8] = o;
    } else {
        // ---- weights -> packed W^T bf16 [br0L1|br1L1|br0L2|br1L2], rel|root rows
        int idx = (b - NB_ADJ - NB_CX) * 256 + t;
        float v = 0.0f;
        if (idx < 2 * W1SZ) {
            int branch = idx / W1SZ, rem = idx - branch * W1SZ;
            int c = rem / KP1, k = rem - c * KP1;
            const float* wr = branch ? f1r : s1r;
            const float* wo = branch ? f1o : s1o;
            if (k < 200) v = (c < 128) ? wr[(size_t)k * 128 + c] : wo[(size_t)k * 128 + (c - 128)];
        } else {
            int i2 = idx - 2 * W1SZ;
            int branch = i2 / W2SZ, rem = i2 - branch * W2SZ;
            int c = rem / HDIM, k = rem - c * HDIM;
            const float* wr = branch ? f2r : s2r;
            const float* wo = branch ? f2o : s2o;
            v = (c < 128) ? wr[(size_t)k * 128 + c] : wo[(size_t)k * 128 + (c - 128)];
        }
        wb[idx] = f2bf(v);
    }
}

// ---------------------------------------------------------------------------
// Round-15: FUSED two-layer kernel.  Evidence (r7): L1/L2 each ~41 µs with
// stage(6.5µs) + compute(~5µs) fully serialized per block (1 block/CU, F1 is
// a dead bubble), plus h (52 MB) and A' (2nd fetch) round-trips.  The L2
// block (g,branch) consumes exactly the L1 block's outputs -> fuse:
//   - h lives in LDS only (never touches HBM)
//   - A' never materialized bf16: stage raw cnt blob (40,960 B) once;
//     expand per-ki 32-wide bf16 windows in LDS during BOTH agg phases
//     (f2bf(count*invdeg) — bitwise identical to prep's old expansion)
//   - one stage bubble per block (90 KB) instead of two (160 KB x2)
// Arena overlays (peak 153,984 B):
//   [0,80000)       X -> Tt -> h -> Tt2 (each overwrite after a barrier
//                   at which the previous tenant is provably dead)
//   [80000,112000)  A' window dbuf 2x16,000 (pitch 40 shorts: (5r+q)%8 spread)
//   [112000,152960) cnt blob (40,000 cnt + 800 invdeg + pad)
//   [152960,153984) zsum1|zsum2
// Fences: F1 = vmcnt(5)+bar (10 X loads retired, 5 cnt loads in flight,
// sched_barrier pins issue order); all others plain __syncthreads().
// Numerics: MFMA order/operands bitwise identical to round-7.
// ---------------------------------------------------------------------------
__global__ __launch_bounds__(512, 1) void fused_kernel(
        const unsigned short* __restrict__ Xb,
        const unsigned short* __restrict__ Wall,
        const unsigned int* __restrict__ Call,
        const float* __restrict__ s1b, const float* __restrict__ f1b,
        const float* __restrict__ s2b, const float* __restrict__ f2b,
        float* __restrict__ z) {
    __shared__ __attribute__((aligned(16))) char arena[ARENA_SZ2];

    const int tid = threadIdx.x;
    const int lane = tid & 63, wid = tid >> 6;   // 8 waves
    const int l15 = lane & 15, quad = lane >> 4;
    const int ms = wid & 1, ns = wid >> 1;       // node half x channel quarter

    const int g = blockIdx.x & 255, branch = blockIdx.x >> 8;

    const unsigned short* Xg = Xb + ((size_t)branch * NG + g) * XSTR1;
    const char* Cg = (const char*)Call + ((size_t)branch * NG + g) * CBLOB;
    const unsigned short* W1 = Wall + (size_t)branch * W1SZ;
    const unsigned short* W2 = Wall + (size_t)2 * W1SZ + (size_t)branch * W2SZ;

    // ---- stage X slab (10 uniform loads), then cnt blob (5 uniform loads)
    {
        __attribute__((address_space(3))) char* lx =
            (__attribute__((address_space(3))) char*)&arena[0];
        for (int j = 0; j <= 9; ++j) {
            int i = (j < 9) ? (j * 512 + tid) : (5000 - 512 + tid);
            const char* gp = (const char*)Xg + (size_t)i * 16;
            __builtin_amdgcn_global_load_lds(
                (const __attribute__((address_space(1))) unsigned int*)gp,
                (__attribute__((address_space(3))) unsigned int*)(lx + (size_t)i * 16),
                16, 0, 0);
        }
        __builtin_amdgcn_sched_barrier(0);
        __attribute__((address_space(3))) char* lc =
            (__attribute__((address_space(3))) char*)&arena[CNTOFF];
        for (int j = 0; j < 5; ++j) {            // 2560 chunks exactly
            int i = j * 512 + tid;
            const char* gp = Cg + (size_t)i * 16;
            __builtin_amdgcn_global_load_lds(
                (const __attribute__((address_space(1))) unsigned int*)gp,
                (__attribute__((address_space(3))) unsigned int*)(lc + (size_t)i * 16),
                16, 0, 0);
        }
    }

    int nrow[7];
#pragma unroll
    for (int mt = 0; mt < 7; ++mt) {
        int s = (ms * 7 + mt) * 16 + l15;
        nrow[mt] = (s > NPG - 1) ? (NPG - 1) : s;   // clamp; killed downstream
    }
    int wrow[2];
#pragma unroll
    for (int nt = 0; nt < 2; ++nt)
        wrow[nt] = (ns * 2 + nt) * 16 + l15;        // ch row 0..127 (W rows & Tt rows)

    // A' window expansion: win[buf][row 200][40 shorts pitch], k in [ki*32,+32)
    auto EXPAND = [&](int ki, int buf) {
        short* wp = (short*)(arena + WINOFF + buf * WINSZ);
#pragma unroll
        for (int j = 0; j < 4; ++j) {
            int w = j * 512 + tid;                  // 1600 words = 200 rows x 8
            if (w < 1600) {
                int row = w >> 3, wj = w & 7;
                int gk0 = ki * 32 + wj * 4;
                unsigned int lo = 0u, hi = 0u;
                if (gk0 < NPG) {                    // 200%4==0: whole word real
                    unsigned int cw = *(const unsigned int*)(arena + CNTOFF + (size_t)(row * 50 + ki * 8 + wj) * 4);
                    float inv = *(const float*)(arena + IDGOFF + (size_t)row * 4);
                    unsigned short b0 = f2bf((float)(cw & 0xFFu) * inv);
                    unsigned short b1 = f2bf((float)((cw >> 8) & 0xFFu) * inv);
                    unsigned short b2 = f2bf((float)((cw >> 16) & 0xFFu) * inv);
                    unsigned short b3 = f2bf((float)((cw >> 24) & 0xFFu) * inv);
                    lo = (unsigned)b0 | ((unsigned)b1 << 16);
                    hi = (unsigned)b2 | ((unsigned)b3 << 16);
                }
                uint2 o; o.x = lo; o.y = hi;
                *(uint2*)(wp + row * 40 + wj * 4) = o;
            }
        }
    };

    // agg phase: acc += Tt(LDS [0,..)) x A'(windows), 7 K-steps
    auto AGG = [&](f32x4 (&acc)[2][7]) {
        EXPAND(0, 0);
        __syncthreads();
#pragma unroll
        for (int ki = 0; ki < 7; ++ki) {
            if (ki < 6) EXPAND(ki + 1, (ki + 1) & 1);
            const short* wp = (const short*)(arena + WINOFF + (ki & 1) * WINSZ);
            const short* Tt = (const short*)arena;
            const int k0 = ki * 32 + quad * 8;
            short8 tf[2];
#pragma unroll
            for (int ct = 0; ct < 2; ++ct)
                tf[ct] = *(const short8*)&Tt[wrow[ct] * TTP + k0];
            short8 afr[7];
#pragma unroll
            for (int dt = 0; dt < 7; ++dt)
                afr[dt] = *(const short8*)(wp + nrow[dt] * 40 + quad * 8);
#pragma unroll
            for (int ct = 0; ct < 2; ++ct)
#pragma unroll
                for (int dt = 0; dt < 7; ++dt)
                    acc[ct][dt] = __builtin_amdgcn_mfma_f32_16x16x32_bf16(
                        tf[ct], afr[dt], acc[ct][dt], 0, 0, 0);
            __syncthreads();
        }
    };

    // T write: acc[m=s][n=c] -> Tt [c 128][s pad 224], cols >=200 zeroed
    auto WRITE_T = [&](f32x4 (&acc)[7][2]) {
        short* Tt = (short*)arena;
#pragma unroll
        for (int mt = 0; mt < 7; ++mt) {
            int s0 = (ms * 7 + mt) * 16 + quad * 4;
#pragma unroll
            for (int nt = 0; nt < 2; ++nt) {
                int c = (ns * 2 + nt) * 16 + l15;
                ushort4 o;
                unsigned short* po = (unsigned short*)&o;
#pragma unroll
                for (int r = 0; r < 4; ++r)
                    po[r] = (s0 + r < NPG) ? f2bf(acc[mt][nt][r]) : (unsigned short)0;
                *(ushort4*)&Tt[c * TTP + s0] = o;
            }
        }
    };

    // ================= L1 =================
    {
        f32x4 accT[7][2], accH[2][7];
#pragma unroll
        for (int mt = 0; mt < 7; ++mt)
#pragma unroll
            for (int nt = 0; nt < 2; ++nt)
#pragma unroll
                for (int r = 0; r < 4; ++r) { accT[mt][nt][r] = 0.0f; accH[nt][mt][r] = 0.0f; }

        // F1: X landed (5 cnt loads still in flight)
        asm volatile("s_waitcnt vmcnt(5)\n\ts_barrier" ::: "memory");

        // phase 2: merged transform + root (X from LDS pitch 400B, W1 direct)
#pragma unroll
        for (int ki = 0; ki < 7; ++ki) {
            int cch = ki * 4 + quad;
            if (cch > 24) cch = 24;                 // never read past staged row
            short8 xf[7];
#pragma unroll
            for (int mt = 0; mt < 7; ++mt)
                xf[mt] = *(const short8*)(arena + nrow[mt] * 400 + cch * 16);
            const int kb = ki * 32 + quad * 8;
            short8 wr[2], wo[2];
#pragma unroll
            for (int nt = 0; nt < 2; ++nt) {
                wr[nt] = *(const short8*)&W1[(size_t)wrow[nt] * KP1 + kb];
                wo[nt] = *(const short8*)&W1[(size_t)(128 + wrow[nt]) * KP1 + kb];
            }
#pragma unroll
            for (int mt = 0; mt < 7; ++mt)
#pragma unroll
                for (int nt = 0; nt < 2; ++nt)
                    accT[mt][nt] = __builtin_amdgcn_mfma_f32_16x16x32_bf16(
                        xf[mt], wr[nt], accT[mt][nt], 0, 0, 0);
#pragma unroll
            for (int nt = 0; nt < 2; ++nt)
#pragma unroll
                for (int mt = 0; mt < 7; ++mt)
                    accH[nt][mt] = __builtin_amdgcn_mfma_f32_16x16x32_bf16(
                        wo[nt], xf[mt], accH[nt][mt], 0, 0, 0);
        }

        __syncthreads();                            // F2: X dead; cnt landed
        WRITE_T(accT);
        if (tid < 256) ((float*)(arena + ZSOFF))[tid] = 0.0f;   // zsum1|zsum2
        __syncthreads();                            // F3: Tt visible

        AGG(accH);                                  // phase 4 (ends with barrier)

        // epilogue: relu+bias, pool -> zsum1, h -> LDS [0,54400) pitch 136
        const float* brel = branch ? f1b : s1b;
        float* zs1 = (float*)(arena + ZSOFF);
        short* hb = (short*)arena;
#pragma unroll
        for (int ct = 0; ct < 2; ++ct) {
            const int c0 = (ns * 2 + ct) * 16 + quad * 4;
            float bb[4], part[4];
#pragma unroll
            for (int r = 0; r < 4; ++r) { bb[r] = brel[c0 + r]; part[r] = 0.0f; }
#pragma unroll
            for (int dt = 0; dt < 7; ++dt) {
                const int d = (ms * 7 + dt) * 16 + l15;
                if (d < NPG) {
                    ushort4 o;
                    unsigned short* po = (unsigned short*)&o;
#pragma unroll
                    for (int r = 0; r < 4; ++r) {
                        float v = fmaxf(accH[ct][dt][r] + bb[r], 0.0f);
                        part[r] += v;
                        po[r] = f2bf(v);
                    }
                    *(ushort4*)&hb[d * HP + c0] = o;
                }
            }
#pragma unroll
            for (int r = 0; r < 4; ++r) {
                float v = part[r];
                v += __shfl_xor(v, 1);
                v += __shfl_xor(v, 2);
                v += __shfl_xor(v, 4);
                v += __shfl_xor(v, 8);
                if (l15 == 0) atomicAdd(&zs1[c0 + r], v);
            }
        }
        __syncthreads();                            // F4: h + zsum1 final
        if (tid < 128)
            z[(size_t)g * 512 + branch * 256 + 0 + tid] =
                zs1[tid] * (branch ? 1.0f : (1.0f / 200.0f));
    }

    // ================= L2 =================
    {
        f32x4 accT[7][2], accH[2][7];
#pragma unroll
        for (int mt = 0; mt < 7; ++mt)
#pragma unroll
            for (int nt = 0; nt < 2; ++nt)
#pragma unroll
                for (int r = 0; r < 4; ++r) { accT[mt][nt][r] = 0.0f; accH[nt][mt][r] = 0.0f; }

        // phase 2: h (LDS pitch 272B, chunks 0..15 all real) x W2 (direct)
#pragma unroll
        for (int ki = 0; ki < 4; ++ki) {
            short8 xf[7];
#pragma unroll
            for (int mt = 0; mt < 7; ++mt)
                xf[mt] = *(const short8*)(arena + nrow[mt] * (HP * 2) + (ki * 4 + quad) * 16);
            const int kb = ki * 32 + quad * 8;
            short8 wr[2], wo[2];
#pragma unroll
            for (int nt = 0; nt < 2; ++nt) {
                wr[nt] = *(const short8*)&W2[(size_t)wrow[nt] * HDIM + kb];
                wo[nt] = *(const short8*)&W2[(size_t)(128 + wrow[nt]) * HDIM + kb];
            }
#pragma unroll
            for (int mt = 0; mt < 7; ++mt)
#pragma unroll
                for (int nt = 0; nt < 2; ++nt)
                    accT[mt][nt] = __builtin_amdgcn_mfma_f32_16x16x32_bf16(
                        xf[mt], wr[nt], accT[mt][nt], 0, 0, 0);
#pragma unroll
            for (int nt = 0; nt < 2; ++nt)
#pragma unroll
                for (int mt = 0; mt < 7; ++mt)
                    accH[nt][mt] = __builtin_amdgcn_mfma_f32_16x16x32_bf16(
                        wo[nt], xf[mt], accH[nt][mt], 0, 0, 0);
        }

        __syncthreads();                            // F5: h dead
        WRITE_T(accT);                              // Tt2 overwrites h region
        __syncthreads();                            // F6: Tt2 visible

        AGG(accH);

        // epilogue: pool only -> zsum2
        const float* brel = branch ? f2b : s2b;
        float* zs2 = (float*)(arena + ZSOFF + 512);
#pragma unroll
        for (int ct = 0; ct < 2; ++ct) {
            const int c0 = (ns * 2 + ct) * 16 + quad * 4;
            float bb[4], part[4];
#pragma unroll
            for (int r = 0; r < 4; ++r) { bb[r] = brel[c0 + r]; part[r] = 0.0f; }
#pragma unroll
            for (int dt = 0; dt < 7; ++dt) {
                const int d = (ms * 7 + dt) * 16 + l15;
                if (d < NPG) {
#pragma unroll
                    for (int r = 0; r < 4; ++r)
                        part[r] += fmaxf(accH[ct][dt][r] + bb[r], 0.0f);
                }
            }
#pragma unroll
            for (int r = 0; r < 4; ++r) {
                float v = part[r];
                v += __shfl_xor(v, 1);
                v += __shfl_xor(v, 2);
                v += __shfl_xor(v, 4);
                v += __shfl_xor(v, 8);
                if (l15 == 0) atomicAdd(&zs2[c0 + r], v);
            }
        }
        __syncthreads();
        if (tid < 128)
            z[(size_t)g * 512 + branch * 256 + 128 + tid] =
                zs2[tid] * (branch ? 1.0f : (1.0f / 200.0f));
    }
}

// ---------------------------------------------------------------------------
// MLP head (fp32): z[512] -> relu(lin1)[128] -> relu(lin2)[64] -> lin3[2]
// -> log_softmax. One block per graph.  (unchanged)
// ---------------------------------------------------------------------------
__global__ __launch_bounds__(128) void mlp_kernel(const float* __restrict__ z,
                                                  const float* __restrict__ w1, const float* __restrict__ b1,
                                                  const float* __restrict__ w2, const float* __restrict__ b2,
                                                  const float* __restrict__ w3, const float* __restrict__ b3,
                                                  float* __restrict__ out) {
    __shared__ float zs[512];
    __shared__ float l1[128];
    __shared__ float l2[64];
    __shared__ float logits[2];
    int g = blockIdx.x, t = threadIdx.x;

#pragma unroll
    for (int i = 0; i < 4; ++i) zs[t + 128 * i] = z[(size_t)g * 512 + t + 128 * i];
    __syncthreads();

    float s = b1[t];
#pragma unroll 8
    for (int k = 0; k < 512; ++k) s = fmaf(zs[k], w1[k * 128 + t], s);
    l1[t] = fmaxf(s, 0.0f);
    __syncthreads();

    if (t < 64) {
        float s2 = b2[t];
#pragma unroll 8
        for (int k = 0; k < 128; ++k) s2 = fmaf(l1[k], w2[k * 64 + t], s2);
        l2[t] = fmaxf(s2, 0.0f);
    }
    __syncthreads();

    if (t < 2) {
        float s3 = b3[t];
        for (int k = 0; k < 64; ++k) s3 = fmaf(l2[k], w3[k * 2 + t], s3);
        logits[t] = s3;
    }
    __syncthreads();

    if (t < 2) {
        float m = fmaxf(logits[0], logits[1]);
        float lse = m + logf(expf(logits[0] - m) + expf(logits[1] - m));
        out[(size_t)g * 2 + t] = logits[t] - lse;
    }
}

// ---------------------------------------------------------------------------
extern "C" void kernel_launch(void* const* d_in, const int* in_sizes, int n_in,
                              void* d_out, int out_size, void* d_ws, size_t ws_size,
                              hipStream_t stream) {
    const float* sc_x = (const float*)d_in[0];
    const float* fc_x = (const float*)d_in[1];
    const int* sc_ei  = (const int*)d_in[2];
    const int* fc_ei  = (const int*)d_in[3];
    const float* sc1_wrel = (const float*)d_in[5];
    const float* sc1_brel = (const float*)d_in[6];
    const float* sc1_wroot = (const float*)d_in[7];
    const float* sc2_wrel = (const float*)d_in[8];
    const float* sc2_brel = (const float*)d_in[9];
    const float* sc2_wroot = (const float*)d_in[10];
    const float* fc1_wrel = (const float*)d_in[11];
    const float* fc1_brel = (const float*)d_in[12];
    const float* fc1_wroot = (const float*)d_in[13];
    const float* fc2_wrel = (const float*)d_in[14];
    const float* fc2_brel = (const float*)d_in[15];
    const float* fc2_wroot = (const float*)d_in[16];
    const float* lin1_w = (const float*)d_in[17];
    const float* lin1_b = (const float*)d_in[18];
    const float* lin2_w = (const float*)d_in[19];
    const float* lin2_b = (const float*)d_in[20];
    const float* lin3_w = (const float*)d_in[21];
    const float* lin3_b = (const float*)d_in[22];

    // Workspace: Xb (bf16 slabs) | Cb (cnt blobs) | Wb | z   (~64 MB)
    unsigned short* Xb = (unsigned short*)d_ws;                  // 2*256*40960 shorts
    unsigned int*  Cb = (unsigned int*)(Xb + (size_t)2 * NG * XSTR1);  // 2*256*10240 u32
    unsigned short* Wb = (unsigned short*)(Cb + (size_t)2 * NG * (CBLOB / 4));
    float* z = (float*)(Wb + (size_t)2 * (W1SZ + W2SZ));         // 256*512 fp32

    prep_kernel<<<NB_PREP, 256, 0, stream>>>(
        sc_ei, fc_ei, sc_x, fc_x,
        sc1_wrel, sc1_wroot, fc1_wrel, fc1_wroot,
        sc2_wrel, sc2_wroot, fc2_wrel, fc2_wroot,
        Cb, Xb, Wb);

    fused_kernel<<<512, 512, 0, stream>>>(
        Xb, Wb, Cb, sc1_brel, fc1_brel, sc2_brel, fc2_brel, z);

    mlp_kernel<<<NG, 128, 0, stream>>>(z, lin1_w, lin1_b, lin2_w, lin2_b,
                                       lin3_w, lin3_b, (float*)d_out);
}

// Round 9
// 253.014 us; speedup vs baseline: 1.0837x; 1.0343x over previous
//
#include <hip/hip_runtime.h>
#include <math.h>

#define NPG   200                 // nodes per graph
#define HDIM  128
#define NG    256
#define NT_T  (NG * NPG)          // 51200
#define EPG_  3200
#define E_T   (NG * EPG_)         // 819200
#define KP1   224                 // layer-1 K (200) padded to mult of 32 (W pitch)
#define TTP   232                 // Tt LDS pitch (shorts): 29 chunks (mod8=5, spread)
#define AFP   232                 // A'full LDS pitch (shorts): same spread
#define HP    136                 // h LDS pitch (shorts): 17 chunks (mod8=1, spread)
#define W1SZ  (256 * KP1)
#define W2SZ  (256 * HDIM)

#define XSTR1 40960               // X slab stride, shorts (81,920 B; data 80,000)
#define CBLOB 40960               // cnt blob bytes/slab: 40,000 cnt + 800 invdeg + 160 pad

// LDS arena (bytes): Af [0,92800) over dead X | Tt/h [92800,152192) over dead
// cnt | cnt [112000,152960) | zsum [152960,153984)
#define TT2OFF 92800
#define CNTOFF 112000
#define IDGOFF (CNTOFF + 40000)   // invdeg f32[200]
#define ZSOFF  152960             // zsum1[128] | zsum2[128] f32
#define ARENA_SZ2 153984

// prep-kernel grid partition
#define NB_ADJ (2 * NG)                       // 512
#define NB_CX  (2 * NG * 5120 / 256)          // 10240
#define NB_CW  ((2 * (W1SZ + W2SZ)) / 256)    // 704
#define NB_PREP (NB_ADJ + NB_CX + NB_CW)

typedef short short8 __attribute__((ext_vector_type(8)));
typedef float f32x4  __attribute__((ext_vector_type(4)));

__device__ __forceinline__ unsigned short f2bf(float f) {
    union { float f; unsigned int u; } v; v.f = f;
    unsigned int u = v.u;
    u += 0x7FFFu + ((u >> 16) & 1u);       // RNE
    return (unsigned short)(u >> 16);
}

// ---------------------------------------------------------------------------
// Prep: [0,512) adjacency -> RAW u8 counts + fp32 invdeg blob; [512,10752)
// X fp32 -> bf16 slabs (pitch 200, stride 40,960 shorts, pad 0);
// [10752,11456) W convert.  (unchanged from round-8)
// ---------------------------------------------------------------------------
__global__ __launch_bounds__(256) void prep_kernel(
        const int* __restrict__ sc_ei, const int* __restrict__ fc_ei,
        const float* __restrict__ sc_x, const float* __restrict__ fc_x,
        const float* __restrict__ s1r, const float* __restrict__ s1o,
        const float* __restrict__ f1r, const float* __restrict__ f1o,
        const float* __restrict__ s2r, const float* __restrict__ s2o,
        const float* __restrict__ f2r, const float* __restrict__ f2o,
        unsigned int* __restrict__ C, unsigned short* __restrict__ xb,
        unsigned short* __restrict__ wb) {
    const int b = blockIdx.x, t = threadIdx.x;

    if (b < NB_ADJ) {
        __shared__ unsigned int cnt[10000];    // 200*200 u8 counters in u32
        __shared__ float invdeg[200];
        const int branch = b >> 8, g = b & 255;
        const int* ei = branch ? fc_ei : sc_ei;

        for (int i = t; i < 10000; i += 256) cnt[i] = 0u;
        __syncthreads();
        const int ebase = g * EPG_;
        for (int i = t; i < EPG_; i += 256) {
            int src = ei[ebase + i];
            int dst = ei[E_T + ebase + i];
            int idx = (dst - g * NPG) * NPG + (src - g * NPG);
            atomicAdd(&cnt[idx >> 2], 1u << ((idx & 3) * 8));
        }
        __syncthreads();
        if (t < NPG) {
            unsigned int s = 0;
            for (int w = 0; w < 50; ++w) {
                unsigned int v = cnt[t * 50 + w];
                s += (v & 0xFFu) + ((v >> 8) & 0xFFu) + ((v >> 16) & 0xFFu) + ((v >> 24) & 0xFFu);
            }
            invdeg[t] = 1.0f / fmaxf((float)s, 1.0f);
        }
        __syncthreads();
        // raw blob out: [10000 cnt u32][200 invdeg f32][40 zero u32]
        unsigned int* Cg = C + (size_t)(branch * NG + g) * (CBLOB / 4);
        for (int q = t; q < 10000; q += 256) Cg[q] = cnt[q];
        if (t < 200) ((float*)(Cg + 10000))[t] = invdeg[t];
        if (t < 40) Cg[10200 + t] = 0u;
    } else if (b < NB_ADJ + NB_CX) {
        // ---- X fp32 [node,200] -> bf16 slabs pitch 200, stride 40960, pad zeroed
        int c = (b - NB_ADJ) * 256 + t;          // 0 .. 2*256*5120-1
        int slab = c / 5120;                     // branch*256 + g
        int ci = c - slab * 5120;                // chunk (8 shorts) within slab
        uint4 o;
        if (ci < 5000) {
            int n  = ci / 25;                    // node within graph
            int k8 = ci - n * 25;
            int branch = slab >> 8, g = slab & 255;
            const float* x = branch ? fc_x : sc_x;
            const float* p = x + ((size_t)g * NPG + n) * 200 + k8 * 8;
            float4 a  = *(const float4*)p;
            float4 bb = *(const float4*)(p + 4);
            o.x = (unsigned)f2bf(a.x) | ((unsigned)f2bf(a.y) << 16);
            o.y = (unsigned)f2bf(a.z) | ((unsigned)f2bf(a.w) << 16);
            o.z = (unsigned)f2bf(bb.x) | ((unsigned)f2bf(bb.y) << 16);
            o.w = (unsigned)f2bf(bb.z) | ((unsigned)f2bf(bb.w) << 16);
        } else {
            o.x = o.y = o.z = o.w = 0u;          // slab pad
        }
        *(uint4*)&xb[(size_t)slab * XSTR1 + (size_t)ci * 8] = o;
    } else {
        // ---- weights -> packed W^T bf16 [br0L1|br1L1|br0L2|br1L2], rel|root rows
        int idx = (b - NB_ADJ - NB_CX) * 256 + t;
        float v = 0.0f;
        if (idx < 2 * W1SZ) {
            int branch = idx / W1SZ, rem = idx - branch * W1SZ;
            int c = rem / KP1, k = rem - c * KP1;
            const float* wr = branch ? f1r : s1r;
            const float* wo = branch ? f1o : s1o;
            if (k < 200) v = (c < 128) ? wr[(size_t)k * 128 + c] : wo[(size_t)k * 128 + (c - 128)];
        } else {
            int i2 = idx - 2 * W1SZ;
            int branch = i2 / W2SZ, rem = i2 - branch * W2SZ;
            int c = rem / HDIM, k = rem - c * HDIM;
            const float* wr = branch ? f2r : s2r;
            const float* wo = branch ? f2o : s2o;
            v = (c < 128) ? wr[(size_t)k * 128 + c] : wo[(size_t)k * 128 + (c - 128)];
        }
        wb[idx] = f2bf(v);
    }
}

// ---------------------------------------------------------------------------
// Round-16: fused kernel, A' expanded ONCE, AGG loops barrier-free.
//
// Evidence (r8): 66.6 µs vs ~3 µs MFMA floor; FETCH 32 MB at 0.5 TB/s (memory
// solved); bank conflicts 4.65M; ~20 barriers incl. 14 inside AGG loops each
// fencing a VALU-heavy EXPAND; A' expanded twice (once per layer).  Fix:
//   - EXPAND_ALL once after F2 into Af[200][232] (92.8 KB over dead X),
//     serving BOTH layers' AGG -> half the expand VALU, no window dbuf
//   - AGG = 7 fully-unrolled pure-LDS-read steps, ZERO internal barriers
//   - 9 barriers total (was ~20)
// Overlay safety: Af writer (EXPAND) reads cnt; Tt writer overwrites cnt
// region only after the EXPAND barrier; h overwrites Tt only after the
// post-AGG barrier; every region's writer is barrier-separated from the
// previous tenant's last reader.
// Numerics: MFMA order/operands bitwise identical to round-8 (Af values are
// the same f2bf(count*invdeg); pads zeroed).
// ---------------------------------------------------------------------------
__global__ __launch_bounds__(512, 1) void fused_kernel(
        const unsigned short* __restrict__ Xb,
        const unsigned short* __restrict__ Wall,
        const unsigned int* __restrict__ Call,
        const float* __restrict__ s1b, const float* __restrict__ f1b,
        const float* __restrict__ s2b, const float* __restrict__ f2b,
        float* __restrict__ z) {
    __shared__ __attribute__((aligned(16))) char arena[ARENA_SZ2];

    const int tid = threadIdx.x;
    const int lane = tid & 63, wid = tid >> 6;   // 8 waves
    const int l15 = lane & 15, quad = lane >> 4;
    const int ms = wid & 1, ns = wid >> 1;       // node half x channel quarter

    const int g = blockIdx.x & 255, branch = blockIdx.x >> 8;

    const unsigned short* Xg = Xb + ((size_t)branch * NG + g) * XSTR1;
    const char* Cg = (const char*)Call + ((size_t)branch * NG + g) * CBLOB;
    const unsigned short* W1 = Wall + (size_t)branch * W1SZ;
    const unsigned short* W2 = Wall + (size_t)2 * W1SZ + (size_t)branch * W2SZ;

    // ---- stage X slab (10 uniform loads), then cnt blob (5 uniform loads)
    {
        __attribute__((address_space(3))) char* lx =
            (__attribute__((address_space(3))) char*)&arena[0];
        for (int j = 0; j <= 9; ++j) {
            int i = (j < 9) ? (j * 512 + tid) : (5000 - 512 + tid);
            const char* gp = (const char*)Xg + (size_t)i * 16;
            __builtin_amdgcn_global_load_lds(
                (const __attribute__((address_space(1))) unsigned int*)gp,
                (__attribute__((address_space(3))) unsigned int*)(lx + (size_t)i * 16),
                16, 0, 0);
        }
        __builtin_amdgcn_sched_barrier(0);
        __attribute__((address_space(3))) char* lc =
            (__attribute__((address_space(3))) char*)&arena[CNTOFF];
        for (int j = 0; j < 5; ++j) {            // 2560 chunks exactly
            int i = j * 512 + tid;
            const char* gp = Cg + (size_t)i * 16;
            __builtin_amdgcn_global_load_lds(
                (const __attribute__((address_space(1))) unsigned int*)gp,
                (__attribute__((address_space(3))) unsigned int*)(lc + (size_t)i * 16),
                16, 0, 0);
        }
    }

    int nrow[7];
#pragma unroll
    for (int mt = 0; mt < 7; ++mt) {
        int s = (ms * 7 + mt) * 16 + l15;
        nrow[mt] = (s > NPG - 1) ? (NPG - 1) : s;   // clamp; killed downstream
    }
    int wrow[2];
#pragma unroll
    for (int nt = 0; nt < 2; ++nt)
        wrow[nt] = (ns * 2 + nt) * 16 + l15;        // ch row 0..127

    // barrier-free agg: acc += Tt x Af, 7 pure-LDS K-steps
    auto AGG = [&](f32x4 (&acc)[2][7]) {
        const short* Tt = (const short*)(arena + TT2OFF);
        const short* Af = (const short*)arena;
#pragma unroll
        for (int ki = 0; ki < 7; ++ki) {
            const int k0 = ki * 32 + quad * 8;
            short8 tf[2];
#pragma unroll
            for (int ct = 0; ct < 2; ++ct)
                tf[ct] = *(const short8*)&Tt[wrow[ct] * TTP + k0];
            short8 afr[7];
#pragma unroll
            for (int dt = 0; dt < 7; ++dt)
                afr[dt] = *(const short8*)&Af[nrow[dt] * AFP + k0];
#pragma unroll
            for (int ct = 0; ct < 2; ++ct)
#pragma unroll
                for (int dt = 0; dt < 7; ++dt)
                    acc[ct][dt] = __builtin_amdgcn_mfma_f32_16x16x32_bf16(
                        tf[ct], afr[dt], acc[ct][dt], 0, 0, 0);
        }
    };

    // T write: acc[m=s][n=c] -> Tt [c 128][s pad 224] at TT2OFF, cols>=200 zero
    auto WRITE_T = [&](f32x4 (&acc)[7][2]) {
        short* Tt = (short*)(arena + TT2OFF);
#pragma unroll
        for (int mt = 0; mt < 7; ++mt) {
            int s0 = (ms * 7 + mt) * 16 + quad * 4;
#pragma unroll
            for (int nt = 0; nt < 2; ++nt) {
                int c = (ns * 2 + nt) * 16 + l15;
                ushort4 o;
                unsigned short* po = (unsigned short*)&o;
#pragma unroll
                for (int r = 0; r < 4; ++r)
                    po[r] = (s0 + r < NPG) ? f2bf(acc[mt][nt][r]) : (unsigned short)0;
                *(ushort4*)&Tt[c * TTP + s0] = o;
            }
        }
    };

    // ================= L1 =================
    {
        f32x4 accT[7][2], accH[2][7];
#pragma unroll
        for (int mt = 0; mt < 7; ++mt)
#pragma unroll
            for (int nt = 0; nt < 2; ++nt)
#pragma unroll
                for (int r = 0; r < 4; ++r) { accT[mt][nt][r] = 0.0f; accH[nt][mt][r] = 0.0f; }

        // F1: X landed (5 cnt loads still in flight)
        asm volatile("s_waitcnt vmcnt(5)\n\ts_barrier" ::: "memory");

        // phase 2: merged transform + root (X from LDS pitch 400B, W1 direct)
#pragma unroll
        for (int ki = 0; ki < 7; ++ki) {
            int cch = ki * 4 + quad;
            if (cch > 24) cch = 24;                 // never read past staged row
            short8 xf[7];
#pragma unroll
            for (int mt = 0; mt < 7; ++mt)
                xf[mt] = *(const short8*)(arena + nrow[mt] * 400 + cch * 16);
            const int kb = ki * 32 + quad * 8;
            short8 wr[2], wo[2];
#pragma unroll
            for (int nt = 0; nt < 2; ++nt) {
                wr[nt] = *(const short8*)&W1[(size_t)wrow[nt] * KP1 + kb];
                wo[nt] = *(const short8*)&W1[(size_t)(128 + wrow[nt]) * KP1 + kb];
            }
#pragma unroll
            for (int mt = 0; mt < 7; ++mt)
#pragma unroll
                for (int nt = 0; nt < 2; ++nt)
                    accT[mt][nt] = __builtin_amdgcn_mfma_f32_16x16x32_bf16(
                        xf[mt], wr[nt], accT[mt][nt], 0, 0, 0);
#pragma unroll
            for (int nt = 0; nt < 2; ++nt)
#pragma unroll
                for (int mt = 0; mt < 7; ++mt)
                    accH[nt][mt] = __builtin_amdgcn_mfma_f32_16x16x32_bf16(
                        wo[nt], xf[mt], accH[nt][mt], 0, 0, 0);
        }

        __syncthreads();   // F2: X dead everywhere; cnt landed (vmcnt drained)

        // EXPAND_ALL: Af[200][AFP], chunks 0..27 (k>=200 zero), over dead X.
        {
            short* Af = (short*)arena;
#pragma unroll
            for (int j = 0; j < 22; ++j) {
                int w = j * 512 + tid;              // 11200 uint2 writes
                if (w < 11200) {
                    int row = w / 56, wj = w - row * 56;   // wj 0..55
                    unsigned int lo = 0u, hi = 0u;
                    if (wj < 50) {                  // k0=wj*4 < 200
                        unsigned int cw = *(const unsigned int*)(arena + CNTOFF + (size_t)(row * 50 + wj) * 4);
                        float inv = *(const float*)(arena + IDGOFF + (size_t)row * 4);
                        unsigned short b0 = f2bf((float)(cw & 0xFFu) * inv);
                        unsigned short b1 = f2bf((float)((cw >> 8) & 0xFFu) * inv);
                        unsigned short b2 = f2bf((float)((cw >> 16) & 0xFFu) * inv);
                        unsigned short b3 = f2bf((float)((cw >> 24) & 0xFFu) * inv);
                        lo = (unsigned)b0 | ((unsigned)b1 << 16);
                        hi = (unsigned)b2 | ((unsigned)b3 << 16);
                    }
                    uint2 o; o.x = lo; o.y = hi;
                    *(uint2*)(Af + row * AFP + wj * 4) = o;
                }
            }
            if (tid < 256) ((float*)(arena + ZSOFF))[tid] = 0.0f;   // zsum1|zsum2
        }
        __syncthreads();   // F3: Af + zsum visible; cnt dead

        WRITE_T(accT);     // Tt over dead cnt region
        __syncthreads();   // F4: Tt visible

        AGG(accH);         // barrier-free
        __syncthreads();   // F5: all waves done reading Tt (h will overwrite)

        // epilogue: relu+bias, pool -> zsum1, h -> LDS at TT2OFF pitch 136
        const float* brel = branch ? f1b : s1b;
        float* zs1 = (float*)(arena + ZSOFF);
        short* hb = (short*)(arena + TT2OFF);
#pragma unroll
        for (int ct = 0; ct < 2; ++ct) {
            const int c0 = (ns * 2 + ct) * 16 + quad * 4;
            float bb[4], part[4];
#pragma unroll
            for (int r = 0; r < 4; ++r) { bb[r] = brel[c0 + r]; part[r] = 0.0f; }
#pragma unroll
            for (int dt = 0; dt < 7; ++dt) {
                const int d = (ms * 7 + dt) * 16 + l15;
                if (d < NPG) {
                    ushort4 o;
                    unsigned short* po = (unsigned short*)&o;
#pragma unroll
                    for (int r = 0; r < 4; ++r) {
                        float v = fmaxf(accH[ct][dt][r] + bb[r], 0.0f);
                        part[r] += v;
                        po[r] = f2bf(v);
                    }
                    *(ushort4*)&hb[d * HP + c0] = o;
                }
            }
#pragma unroll
            for (int r = 0; r < 4; ++r) {
                float v = part[r];
                v += __shfl_xor(v, 1);
                v += __shfl_xor(v, 2);
                v += __shfl_xor(v, 4);
                v += __shfl_xor(v, 8);
                if (l15 == 0) atomicAdd(&zs1[c0 + r], v);
            }
        }
        __syncthreads();   // F6: h + zsum1 final
        if (tid < 128)
            z[(size_t)g * 512 + branch * 256 + 0 + tid] =
                zs1[tid] * (branch ? 1.0f : (1.0f / 200.0f));
    }

    // ================= L2 =================
    {
        f32x4 accT[7][2], accH[2][7];
#pragma unroll
        for (int mt = 0; mt < 7; ++mt)
#pragma unroll
            for (int nt = 0; nt < 2; ++nt)
#pragma unroll
                for (int r = 0; r < 4; ++r) { accT[mt][nt][r] = 0.0f; accH[nt][mt][r] = 0.0f; }

        // phase 2: h (LDS pitch 272B, chunks 0..15 all real) x W2 (direct)
#pragma unroll
        for (int ki = 0; ki < 4; ++ki) {
            short8 xf[7];
#pragma unroll
            for (int mt = 0; mt < 7; ++mt)
                xf[mt] = *(const short8*)(arena + TT2OFF + nrow[mt] * (HP * 2) + (ki * 4 + quad) * 16);
            const int kb = ki * 32 + quad * 8;
            short8 wr[2], wo[2];
#pragma unroll
            for (int nt = 0; nt < 2; ++nt) {
                wr[nt] = *(const short8*)&W2[(size_t)wrow[nt] * HDIM + kb];
                wo[nt] = *(const short8*)&W2[(size_t)(128 + wrow[nt]) * HDIM + kb];
            }
#pragma unroll
            for (int mt = 0; mt < 7; ++mt)
#pragma unroll
                for (int nt = 0; nt < 2; ++nt)
                    accT[mt][nt] = __builtin_amdgcn_mfma_f32_16x16x32_bf16(
                        xf[mt], wr[nt], accT[mt][nt], 0, 0, 0);
#pragma unroll
            for (int nt = 0; nt < 2; ++nt)
#pragma unroll
                for (int mt = 0; mt < 7; ++mt)
                    accH[nt][mt] = __builtin_amdgcn_mfma_f32_16x16x32_bf16(
                        wo[nt], xf[mt], accH[nt][mt], 0, 0, 0);
        }

        __syncthreads();   // F7: h dead
        WRITE_T(accT);     // Tt2 overwrites h region
        __syncthreads();   // F8: Tt2 visible

        AGG(accH);         // barrier-free; Af still valid

        // epilogue: pool only -> zsum2 (separate region; no Tt-write hazard)
        const float* brel = branch ? f2b : s2b;
        float* zs2 = (float*)(arena + ZSOFF + 512);
#pragma unroll
        for (int ct = 0; ct < 2; ++ct) {
            const int c0 = (ns * 2 + ct) * 16 + quad * 4;
            float bb[4], part[4];
#pragma unroll
            for (int r = 0; r < 4; ++r) { bb[r] = brel[c0 + r]; part[r] = 0.0f; }
#pragma unroll
            for (int dt = 0; dt < 7; ++dt) {
                const int d = (ms * 7 + dt) * 16 + l15;
                if (d < NPG) {
#pragma unroll
                    for (int r = 0; r < 4; ++r)
                        part[r] += fmaxf(accH[ct][dt][r] + bb[r], 0.0f);
                }
            }
#pragma unroll
            for (int r = 0; r < 4; ++r) {
                float v = part[r];
                v += __shfl_xor(v, 1);
                v += __shfl_xor(v, 2);
                v += __shfl_xor(v, 4);
                v += __shfl_xor(v, 8);
                if (l15 == 0) atomicAdd(&zs2[c0 + r], v);
            }
        }
        __syncthreads();   // F9: zsum2 complete
        if (tid < 128)
            z[(size_t)g * 512 + branch * 256 + 128 + tid] =
                zs2[tid] * (branch ? 1.0f : (1.0f / 200.0f));
    }
}

// ---------------------------------------------------------------------------
// MLP head (fp32): z[512] -> relu(lin1)[128] -> relu(lin2)[64] -> lin3[2]
// -> log_softmax. One block per graph.  (unchanged)
// ---------------------------------------------------------------------------
__global__ __launch_bounds__(128) void mlp_kernel(const float* __restrict__ z,
                                                  const float* __restrict__ w1, const float* __restrict__ b1,
                                                  const float* __restrict__ w2, const float* __restrict__ b2,
                                                  const float* __restrict__ w3, const float* __restrict__ b3,
                                                  float* __restrict__ out) {
    __shared__ float zs[512];
    __shared__ float l1[128];
    __shared__ float l2[64];
    __shared__ float logits[2];
    int g = blockIdx.x, t = threadIdx.x;

#pragma unroll
    for (int i = 0; i < 4; ++i) zs[t + 128 * i] = z[(size_t)g * 512 + t + 128 * i];
    __syncthreads();

    float s = b1[t];
#pragma unroll 8
    for (int k = 0; k < 512; ++k) s = fmaf(zs[k], w1[k * 128 + t], s);
    l1[t] = fmaxf(s, 0.0f);
    __syncthreads();

    if (t < 64) {
        float s2 = b2[t];
#pragma unroll 8
        for (int k = 0; k < 128; ++k) s2 = fmaf(l1[k], w2[k * 64 + t], s2);
        l2[t] = fmaxf(s2, 0.0f);
    }
    __syncthreads();

    if (t < 2) {
        float s3 = b3[t];
        for (int k = 0; k < 64; ++k) s3 = fmaf(l2[k], w3[k * 2 + t], s3);
        logits[t] = s3;
    }
    __syncthreads();

    if (t < 2) {
        float m = fmaxf(logits[0], logits[1]);
        float lse = m + logf(expf(logits[0] - m) + expf(logits[1] - m));
        out[(size_t)g * 2 + t] = logits[t] - lse;
    }
}

// ---------------------------------------------------------------------------
extern "C" void kernel_launch(void* const* d_in, const int* in_sizes, int n_in,
                              void* d_out, int out_size, void* d_ws, size_t ws_size,
                              hipStream_t stream) {
    const float* sc_x = (const float*)d_in[0];
    const float* fc_x = (const float*)d_in[1];
    const int* sc_ei  = (const int*)d_in[2];
    const int* fc_ei  = (const int*)d_in[3];
    const float* sc1_wrel = (const float*)d_in[5];
    const float* sc1_brel = (const float*)d_in[6];
    const float* sc1_wroot = (const float*)d_in[7];
    const float* sc2_wrel = (const float*)d_in[8];
    const float* sc2_brel = (const float*)d_in[9];
    const float* sc2_wroot = (const float*)d_in[10];
    const float* fc1_wrel = (const float*)d_in[11];
    const float* fc1_brel = (const float*)d_in[12];
    const float* fc1_wroot = (const float*)d_in[13];
    const float* fc2_wrel = (const float*)d_in[14];
    const float* fc2_brel = (const float*)d_in[15];
    const float* fc2_wroot = (const float*)d_in[16];
    const float* lin1_w = (const float*)d_in[17];
    const float* lin1_b = (const float*)d_in[18];
    const float* lin2_w = (const float*)d_in[19];
    const float* lin2_b = (const float*)d_in[20];
    const float* lin3_w = (const float*)d_in[21];
    const float* lin3_b = (const float*)d_in[22];

    // Workspace: Xb (bf16 slabs) | Cb (cnt blobs) | Wb | z   (~64 MB)
    unsigned short* Xb = (unsigned short*)d_ws;                  // 2*256*40960 shorts
    unsigned int*  Cb = (unsigned int*)(Xb + (size_t)2 * NG * XSTR1);  // 2*256*10240 u32
    unsigned short* Wb = (unsigned short*)(Cb + (size_t)2 * NG * (CBLOB / 4));
    float* z = (float*)(Wb + (size_t)2 * (W1SZ + W2SZ));         // 256*512 fp32

    prep_kernel<<<NB_PREP, 256, 0, stream>>>(
        sc_ei, fc_ei, sc_x, fc_x,
        sc1_wrel, sc1_wroot, fc1_wrel, fc1_wroot,
        sc2_wrel, sc2_wroot, fc2_wrel, fc2_wroot,
        Cb, Xb, Wb);

    fused_kernel<<<512, 512, 0, stream>>>(
        Xb, Wb, Cb, sc1_brel, fc1_brel, sc2_brel, fc2_brel, z);

    mlp_kernel<<<NG, 128, 0, stream>>>(z, lin1_w, lin1_b, lin2_w, lin2_b,
                                       lin3_w, lin3_b, (float*)d_out);
}